// Round 5
// baseline (171.000 us; speedup 1.0000x reference)
//
#include <hip/hip_runtime.h>

#define H_DIM 1024
#define I_DIM 512
#define E_EXP 16
#define BM    128
#define BK    64
#define BSTR  68   // Bs row stride in shorts (64 + 4 pad -> stride 34 dwords ≡ 2 mod 32)

using bf16x8   = __attribute__((ext_vector_type(8))) short;
using floatx4  = __attribute__((ext_vector_type(4))) float;
using ushort4v = __attribute__((ext_vector_type(4))) unsigned short;

struct BvT { float4 a, b, c, d; };   // 4 k-rows x 4 cols, named members: SSA, cannot spill via alloca

__device__ __forceinline__ unsigned short f2bf(float f) {
  union { float f; unsigned u; } v; v.f = f;
  return (unsigned short)((v.u + 0x7FFFu + ((v.u >> 16) & 1u)) >> 16);  // RNE
}
__device__ __forceinline__ unsigned pk2(float a, float b) {
  return (unsigned)f2bf(a) | ((unsigned)f2bf(b) << 16);
}

__device__ __forceinline__ void gld16(const void* g, void* l) {
  __builtin_amdgcn_global_load_lds((const __attribute__((address_space(1))) void*)g,
                                   (__attribute__((address_space(3))) void*)l,
                                   16, 0, 0);
}

// barrier draining LDS ops only (all vmem stays in flight)
__device__ __forceinline__ void bar_lgkm() {
  asm volatile("s_waitcnt lgkmcnt(0)" ::: "memory");
  __builtin_amdgcn_sched_barrier(0);
  __builtin_amdgcn_s_barrier();
  __builtin_amdgcn_sched_barrier(0);
}
// step barrier: drain A-stage gld16 (4), keep newest 4 B-prefetch loads flying
__device__ __forceinline__ void bar_v4() {
  asm volatile("s_waitcnt vmcnt(4) lgkmcnt(0)" ::: "memory");
  __builtin_amdgcn_sched_barrier(0);
  __builtin_amdgcn_s_barrier();
  __builtin_amdgcn_sched_barrier(0);
}
// final drain
__device__ __forceinline__ void bar_v0() {
  asm volatile("s_waitcnt vmcnt(0) lgkmcnt(0)" ::: "memory");
  __builtin_amdgcn_sched_barrier(0);
  __builtin_amdgcn_s_barrier();
  __builtin_amdgcn_sched_barrier(0);
}

__device__ __forceinline__ bool tile_info(const int* __restrict__ counts, int by,
                                          int& e, int& row0, int& base, int& cnt) {
  int acc = 0, off = 0;
  e = -1;
  #pragma unroll
  for (int i = 0; i < E_EXP; ++i) {
    int c = counts[i];
    int nt = (c + BM - 1) >> 7;
    if (e < 0 && by < acc + nt) { e = i; row0 = (by - acc) * BM; base = off; cnt = c; }
    acc += nt; off += c;
  }
  return e >= 0;
}

// ---------------- x: fp32 -> bf16 (streaming) ----------------
__global__ void k_cvt(const float* __restrict__ x, unsigned short* __restrict__ xb) {
  const float4* s4 = (const float4*)x;
  int b0 = blockIdx.x * 512 + threadIdx.x;
  float4 a = s4[b0];
  float4 b = s4[b0 + 256];
  ushort4v oa, ob;
  oa.x = f2bf(a.x); oa.y = f2bf(a.y); oa.z = f2bf(a.z); oa.w = f2bf(a.w);
  ob.x = f2bf(b.x); ob.y = f2bf(b.y); ob.z = f2bf(b.z); ob.w = f2bf(b.w);
  ((ushort4v*)xb)[b0] = oa;
  ((ushort4v*)xb)[b0 + 256] = ob;
}

// B tile load: 4 consecutive k-rows, this thread's 4 cols (16 B) each — one latency batch
__device__ __forceinline__ BvT ldB(const float* gptr, int kidx, int rstride) {
  BvT r;
  r.a = *(const float4*)&gptr[(size_t)(kidx + 0) * rstride];
  r.b = *(const float4*)&gptr[(size_t)(kidx + 1) * rstride];
  r.c = *(const float4*)&gptr[(size_t)(kidx + 2) * rstride];
  r.d = *(const float4*)&gptr[(size_t)(kidx + 3) * rstride];
  return r;
}
// convert + transposed store into Bs: 4 rows (cols), stride 34 dwords
__device__ __forceinline__ void stB(unsigned int* dst, BvT v) {
  uint2 d;
  d.x = pk2(v.a.x, v.b.x); d.y = pk2(v.c.x, v.d.x); *(uint2*)&dst[0 * (BSTR/2)] = d;
  d.x = pk2(v.a.y, v.b.y); d.y = pk2(v.c.y, v.d.y); *(uint2*)&dst[1 * (BSTR/2)] = d;
  d.x = pk2(v.a.z, v.b.z); d.y = pk2(v.c.z, v.d.z); *(uint2*)&dst[2 * (BSTR/2)] = d;
  d.x = pk2(v.a.w, v.b.w); d.y = pk2(v.c.w, v.d.w); *(uint2*)&dst[3 * (BSTR/2)] = d;
}

// ---------------- GEMM A: h = silu(x@Wg)*(x@Wu) ----------------
// 32-col tiles, grid 768 (striped decode). 2-deep B prefetch: ldB(s+2) issued at
// step s, stB'd at step s+1 => >1 K-step of vmem flight over compulsory HBM misses.
// Issue order pinned A-then-B so bar_v4's vmcnt(4) drains A, keeps newest B flying.
__launch_bounds__(256, 3)
__global__ void k_gemm_a(const unsigned short* __restrict__ xb,
                         const float* __restrict__ wgu,
                         unsigned short* __restrict__ hb,
                         const int* __restrict__ counts) {
  __shared__ unsigned short As[2][BM * BK];   // 32 KB
  __shared__ unsigned short Bs[64 * BSTR];    // 8.7 KB; rows 0-31 g, 32-63 u

  const int gid = blockIdx.x;
  const int by = gid % 48, bx = gid / 48;     // stripe empties across CUs
  int e, row0, base, cnt;
  if (!tile_info(counts, by, e, row0, base, cnt)) return;
  const int rows = (cnt - row0 < BM) ? (cnt - row0) : BM;
  const int c0 = bx * 32;

  const int tid = threadIdx.x;
  const int w = tid >> 6, l = tid & 63;
  const int lr = l & 15, q = l >> 4;
  const int asr = l >> 3;                     // A staging: LDS slot row in 8-row group
  const int akc = ((l & 7) ^ asr) * 8;        // XOR-swizzled global 16B chunk (shorts)
  const int cswz = lr & 7;                    // A read-side swizzle key

  // B staging: thread owns 4 cols (f4) of g-or-u (seg), k rows kb..kb+3
  const int f4  = tid & 7;
  const int seg = (tid >> 3) & 1;
  const int kb  = (tid >> 4) * 4;
  const float* gptr = wgu + (size_t)e * H_DIM * (2 * I_DIM) + c0 + f4 * 4 + seg * I_DIM;
  unsigned int* bsd = (unsigned int*)Bs + (seg * 32 + f4 * 4) * (BSTR / 2) + (kb >> 1);

  const int mhalf = w & 1, nhalf = w >> 1;
  const int mrow = mhalf * 64;
  const unsigned short* arow = xb + (size_t)(base + row0) * H_DIM;

  int agr0, agr1, agr2, agr3;
  {
    int r0 = w * 32 + asr,      r1 = r0 + 8, r2 = r0 + 16, r3 = r0 + 24;
    agr0 = (r0 < rows) ? r0 : rows - 1;
    agr1 = (r1 < rows) ? r1 : rows - 1;
    agr2 = (r2 < rows) ? r2 : rows - 1;
    agr3 = (r3 < rows) ? r3 : rows - 1;
  }

  floatx4 accg[4], accu[4];
  #pragma unroll
  for (int i = 0; i < 4; ++i) { accg[i] = (floatx4){0,0,0,0}; accu[i] = (floatx4){0,0,0,0}; }

  auto loadA = [&](int kk, int buf) {
    gld16(&arow[(size_t)agr0 * H_DIM + kk + akc], &As[buf][(w * 32 +  0) * BK]);
    gld16(&arow[(size_t)agr1 * H_DIM + kk + akc], &As[buf][(w * 32 +  8) * BK]);
    gld16(&arow[(size_t)agr2 * H_DIM + kk + akc], &As[buf][(w * 32 + 16) * BK]);
    gld16(&arow[(size_t)agr3 * H_DIM + kk + akc], &As[buf][(w * 32 + 24) * BK]);
  };
  auto compute = [&](int cb) {
    #pragma unroll
    for (int kf = 0; kf < 2; ++kf) {
      const int c = kf * 4 + q;
      const int ca = (c ^ cswz) * 8;
      const int ch = c * 8;
      bf16x8 af[4], bg, bu;
      #pragma unroll
      for (int mi = 0; mi < 4; ++mi)
        af[mi] = *(const bf16x8*)&As[cb][(mrow + mi * 16 + lr) * BK + ca];
      bg = *(const bf16x8*)&Bs[(nhalf * 16 + lr) * BSTR + ch];
      bu = *(const bf16x8*)&Bs[(32 + nhalf * 16 + lr) * BSTR + ch];
      #pragma unroll
      for (int mi = 0; mi < 4; ++mi) {
        accg[mi] = __builtin_amdgcn_mfma_f32_16x16x32_bf16(af[mi], bg, accg[mi], 0, 0, 0);
        accu[mi] = __builtin_amdgcn_mfma_f32_16x16x32_bf16(af[mi], bu, accu[mi], 0, 0, 0);
      }
    }
  };

  // ---- prologue: queue [B0(4), A0(4), B1(4)] ----
  BvT b0 = ldB(gptr, 0 * BK + kb, 2 * I_DIM);
  loadA(0, 0);
  BvT b1 = ldB(gptr, 1 * BK + kb, 2 * I_DIM);
  stB(bsd, b0);               // waits vmcnt(8): b0 regs ready
  bar_v4();                   // A0 done; B1 stays flying
  int cur = 0;

  // ---- main: steps 0..13 as 7 double-steps ----
  #pragma unroll 1
  for (int i = 0; i < 7; ++i) {
    const int s = 2 * i;
    // even step s: Bs=tile s, b1=B(s+1)
    loadA((s + 1) * BK, cur ^ 1);
    __builtin_amdgcn_sched_barrier(0);
    b0 = ldB(gptr, (s + 2) * BK + kb, 2 * I_DIM);
    __builtin_amdgcn_sched_barrier(0);
    compute(cur);
    bar_lgkm();
    stB(bsd, b1);             // vmcnt(8): A(s+1), b0 keep flying
    bar_v4();                 // A(s+1) done; b0 flying
    cur ^= 1;
    // odd step s+1: Bs=tile s+1, b0=B(s+2)
    loadA((s + 2) * BK, cur ^ 1);
    __builtin_amdgcn_sched_barrier(0);
    b1 = ldB(gptr, (s + 3) * BK + kb, 2 * I_DIM);
    __builtin_amdgcn_sched_barrier(0);
    compute(cur);
    bar_lgkm();
    stB(bsd, b0);
    bar_v4();
    cur ^= 1;
  }
  // ---- step 14: no more B loads; b1 = B(15) ----
  loadA(15 * BK, cur ^ 1);
  __builtin_amdgcn_sched_barrier(0);
  compute(cur);               // tile 14
  bar_lgkm();
  stB(bsd, b1);               // tile 15
  bar_v0();
  cur ^= 1;
  compute(cur);               // tile 15

  #pragma unroll
  for (int mi = 0; mi < 4; ++mi)
    #pragma unroll
    for (int r = 0; r < 4; ++r) {
      int row_local = mrow + mi * 16 + q * 4 + r;
      if (row_local >= rows) continue;
      size_t orow = (size_t)(base + row0 + row_local) * I_DIM;
      float g = accg[mi][r], u = accu[mi][r];
      float s = g / (1.0f + __expf(-g)) * u;
      hb[orow + c0 + nhalf * 16 + lr] = f2bf(s);
    }
}

// ---------------- GEMM B: out = h @ Wd (same pipeline, nk=8) ----------------
__launch_bounds__(256, 3)
__global__ void k_gemm_b(const unsigned short* __restrict__ hb,
                         const float* __restrict__ wdn,
                         float* __restrict__ out,
                         const int* __restrict__ counts) {
  __shared__ unsigned short As[2][BM * BK];
  __shared__ unsigned short Bs[64 * BSTR];

  const int gid = blockIdx.x;
  const int by = gid % 48, bx = gid / 48;
  int e, row0, base, cnt;
  if (!tile_info(counts, by, e, row0, base, cnt)) return;
  const int rows = (cnt - row0 < BM) ? (cnt - row0) : BM;
  const int n0 = bx * 64;

  const int tid = threadIdx.x;
  const int w = tid >> 6, l = tid & 63;
  const int lr = l & 15, q = l >> 4;
  const int asr = l >> 3;
  const int akc = ((l & 7) ^ asr) * 8;
  const int cswz = lr & 7;

  const int f4 = tid & 15;
  const int kb = (tid >> 4) * 4;
  const float* gptr = wdn + (size_t)e * I_DIM * H_DIM + n0 + f4 * 4;
  unsigned int* bsd = (unsigned int*)Bs + (f4 * 4) * (BSTR / 2) + (kb >> 1);

  const int mhalf = w & 1, nhalf = w >> 1;
  const int mrow = mhalf * 64;
  const unsigned short* arow = hb + (size_t)(base + row0) * I_DIM;

  int agr0, agr1, agr2, agr3;
  {
    int r0 = w * 32 + asr,      r1 = r0 + 8, r2 = r0 + 16, r3 = r0 + 24;
    agr0 = (r0 < rows) ? r0 : rows - 1;
    agr1 = (r1 < rows) ? r1 : rows - 1;
    agr2 = (r2 < rows) ? r2 : rows - 1;
    agr3 = (r3 < rows) ? r3 : rows - 1;
  }

  floatx4 acc[4][2];
  #pragma unroll
  for (int i = 0; i < 4; ++i)
    #pragma unroll
    for (int j = 0; j < 2; ++j) acc[i][j] = (floatx4){0,0,0,0};

  auto loadA = [&](int kk, int buf) {
    gld16(&arow[(size_t)agr0 * I_DIM + kk + akc], &As[buf][(w * 32 +  0) * BK]);
    gld16(&arow[(size_t)agr1 * I_DIM + kk + akc], &As[buf][(w * 32 +  8) * BK]);
    gld16(&arow[(size_t)agr2 * I_DIM + kk + akc], &As[buf][(w * 32 + 16) * BK]);
    gld16(&arow[(size_t)agr3 * I_DIM + kk + akc], &As[buf][(w * 32 + 24) * BK]);
  };
  auto compute = [&](int cb) {
    #pragma unroll
    for (int kf = 0; kf < 2; ++kf) {
      const int c = kf * 4 + q;
      const int ca = (c ^ cswz) * 8;
      const int ch = c * 8;
      bf16x8 af[4], bf[2];
      #pragma unroll
      for (int mi = 0; mi < 4; ++mi)
        af[mi] = *(const bf16x8*)&As[cb][(mrow + mi * 16 + lr) * BK + ca];
      #pragma unroll
      for (int ni = 0; ni < 2; ++ni)
        bf[ni] = *(const bf16x8*)&Bs[(nhalf * 32 + ni * 16 + lr) * BSTR + ch];
      #pragma unroll
      for (int mi = 0; mi < 4; ++mi)
        #pragma unroll
        for (int ni = 0; ni < 2; ++ni)
          acc[mi][ni] = __builtin_amdgcn_mfma_f32_16x16x32_bf16(af[mi], bf[ni], acc[mi][ni], 0, 0, 0);
    }
  };

  // prologue
  BvT b0 = ldB(gptr, 0 * BK + kb, H_DIM);
  loadA(0, 0);
  BvT b1 = ldB(gptr, 1 * BK + kb, H_DIM);
  stB(bsd, b0);
  bar_v4();
  int cur = 0;

  // steps 0..5 as 3 double-steps
  #pragma unroll 1
  for (int i = 0; i < 3; ++i) {
    const int s = 2 * i;
    loadA((s + 1) * BK, cur ^ 1);
    __builtin_amdgcn_sched_barrier(0);
    b0 = ldB(gptr, (s + 2) * BK + kb, H_DIM);
    __builtin_amdgcn_sched_barrier(0);
    compute(cur);
    bar_lgkm();
    stB(bsd, b1);
    bar_v4();
    cur ^= 1;
    loadA((s + 2) * BK, cur ^ 1);
    __builtin_amdgcn_sched_barrier(0);
    b1 = ldB(gptr, (s + 3) * BK + kb, H_DIM);
    __builtin_amdgcn_sched_barrier(0);
    compute(cur);
    bar_lgkm();
    stB(bsd, b0);
    bar_v4();
    cur ^= 1;
  }
  // step 6: b1 = B(7)
  loadA(7 * BK, cur ^ 1);
  __builtin_amdgcn_sched_barrier(0);
  compute(cur);               // tile 6
  bar_lgkm();
  stB(bsd, b1);               // tile 7
  bar_v0();
  cur ^= 1;
  compute(cur);               // tile 7

  #pragma unroll
  for (int mi = 0; mi < 4; ++mi)
    #pragma unroll
    for (int r = 0; r < 4; ++r) {
      int row_local = mrow + mi * 16 + q * 4 + r;
      if (row_local >= rows) continue;
      size_t orow = (size_t)(base + row0 + row_local) * H_DIM;
      #pragma unroll
      for (int ni = 0; ni < 2; ++ni)
        out[orow + n0 + nhalf * 32 + ni * 16 + lr] = acc[mi][ni][r];
    }
}

// ---------------- launch ----------------
extern "C" void kernel_launch(void* const* d_in, const int* in_sizes, int n_in,
                              void* d_out, int out_size, void* d_ws, size_t ws_size,
                              hipStream_t stream) {
  const float* x      = (const float*)d_in[0];
  const float* wgu    = (const float*)d_in[1];
  const float* wdn    = (const float*)d_in[2];
  const int*   counts = (const int*)d_in[3];
  float* out = (float*)d_out;

  unsigned char* ws = (unsigned char*)d_ws;
  unsigned short* xb = (unsigned short*)(ws);            // 8 MB
  unsigned short* hb = (unsigned short*)(ws + 8388608);  // 4 MB

  k_cvt<<<2048, 256, 0, stream>>>(x, xb);
  k_gemm_a<<<768, 256, 0, stream>>>(xb, wgu, hb, counts);   // 16 x-blocks * 48 y (striped)
  k_gemm_b<<<768, 256, 0, stream>>>(hb, wdn, out, counts);  // 16 x-blocks * 48 y (striped)
}

// Round 6
// 170.790 us; speedup vs baseline: 1.0012x; 1.0012x over previous
//
#include <hip/hip_runtime.h>

#define H_DIM 1024
#define I_DIM 512
#define E_EXP 16
#define BM    128
#define BK    64
// Bs: stride 64 shorts, ZERO pad; bank conflicts handled by chunk-XOR swizzle
// (chunk ^= row&7), same involution on write (stB) and read (ca). LDS total
// = 32768 (As dbuf) + 8192 (Bs) = 40960 exactly -> 4 blocks/CU.

using bf16x8   = __attribute__((ext_vector_type(8))) short;
using floatx4  = __attribute__((ext_vector_type(4))) float;
using ushort4v = __attribute__((ext_vector_type(4))) unsigned short;

__device__ __forceinline__ unsigned short f2bf(float f) {
  union { float f; unsigned u; } v; v.f = f;
  return (unsigned short)((v.u + 0x7FFFu + ((v.u >> 16) & 1u)) >> 16);  // RNE
}
__device__ __forceinline__ unsigned pk2(float a, float b) {
  return (unsigned)f2bf(a) | ((unsigned)f2bf(b) << 16);
}

__device__ __forceinline__ void gld16(const void* g, void* l) {
  __builtin_amdgcn_global_load_lds((const __attribute__((address_space(1))) void*)g,
                                   (__attribute__((address_space(3))) void*)l,
                                   16, 0, 0);
}

// barrier draining LDS ops only (vmem prefetch stays in flight)
__device__ __forceinline__ void bar_lgkm() {
  asm volatile("s_waitcnt lgkmcnt(0)" ::: "memory");
  __builtin_amdgcn_sched_barrier(0);
  __builtin_amdgcn_s_barrier();
  __builtin_amdgcn_sched_barrier(0);
}
// full drain — once per K-step
__device__ __forceinline__ void bar_full() {
  asm volatile("s_waitcnt vmcnt(0) lgkmcnt(0)" ::: "memory");
  __builtin_amdgcn_sched_barrier(0);
  __builtin_amdgcn_s_barrier();
  __builtin_amdgcn_sched_barrier(0);
}

__device__ __forceinline__ bool tile_info(const int* __restrict__ counts, int by,
                                          int& e, int& row0, int& base, int& cnt) {
  int acc = 0, off = 0;
  e = -1;
  #pragma unroll
  for (int i = 0; i < E_EXP; ++i) {
    int c = counts[i];
    int nt = (c + BM - 1) >> 7;
    if (e < 0 && by < acc + nt) { e = i; row0 = (by - acc) * BM; base = off; cnt = c; }
    acc += nt; off += c;
  }
  return e >= 0;
}

// ---------------- x: fp32 -> bf16 (streaming) ----------------
__global__ void k_cvt(const float* __restrict__ x, unsigned short* __restrict__ xb) {
  const float4* s4 = (const float4*)x;
  int b0 = blockIdx.x * 512 + threadIdx.x;
  float4 a = s4[b0];
  float4 b = s4[b0 + 256];
  ushort4v oa, ob;
  oa.x = f2bf(a.x); oa.y = f2bf(a.y); oa.z = f2bf(a.z); oa.w = f2bf(a.w);
  ob.x = f2bf(b.x); ob.y = f2bf(b.y); ob.z = f2bf(b.z); ob.w = f2bf(b.w);
  ((ushort4v*)xb)[b0] = oa;
  ((ushort4v*)xb)[b0 + 256] = ob;
}

// ---------------- GEMM A: h = silu(x@Wg)*(x@Wu) ----------------
// Round-4 structure (measured best: 44 us), occupancy 3 -> 4 blocks/CU via
// zero-pad swizzled Bs. Per step: loadB(regs)+loadA(gld16) -> compute ->
// bar_lgkm -> convert+write Bs -> bar_full.
__launch_bounds__(256, 4)
__global__ void k_gemm_a(const unsigned short* __restrict__ xb,
                         const float* __restrict__ wgu,
                         unsigned short* __restrict__ hb,
                         const int* __restrict__ counts) {
  __shared__ unsigned short As[2][BM * BK];   // 32 KB
  __shared__ unsigned short Bs[64 * BK];      // 8 KB; rows 0-31 g, 32-63 u (swizzled chunks)

  int e, row0, base, cnt;
  if (!tile_info(counts, blockIdx.y, e, row0, base, cnt)) return;
  const int rows = (cnt - row0 < BM) ? (cnt - row0) : BM;
  const int c0 = blockIdx.x * 32;

  const int tid = threadIdx.x;
  const int w = tid >> 6, l = tid & 63;
  const int lr = l & 15, q = l >> 4;
  const int asr = l >> 3;                     // A staging: LDS slot row in 8-row group
  const int akc = ((l & 7) ^ asr) * 8;        // XOR-swizzled global 16B chunk (shorts)
  const int cswz = lr & 7;                    // read-side swizzle key (A and B)

  // B staging: thread owns 4 cols (f4) of g-or-u (seg), k rows kb..kb+3
  const int f4  = tid & 7;
  const int seg = (tid >> 3) & 1;
  const int kb  = (tid >> 4) * 4;             // 0..60
  const int rb0 = seg * 32 + f4 * 4;          // first owned Bs row
  const float* gptr = wgu + (size_t)e * H_DIM * (2 * I_DIM) + c0 + f4 * 4 + seg * I_DIM;
  unsigned int* BsD = (unsigned int*)Bs;
  const int cwk = kb >> 3;                    // k-chunk of this thread's write
  const int din = (kb >> 1) & 3;              // dword within chunk (0 or 2)

  const int mhalf = w & 1, nhalf = w >> 1;
  const int mrow = mhalf * 64;
  const unsigned short* arow = xb + (size_t)(base + row0) * H_DIM;

  int agr[4];
  #pragma unroll
  for (int t = 0; t < 4; ++t) {
    int r = w * 32 + t * 8 + asr;
    agr[t] = (r < rows) ? r : rows - 1;
  }

  floatx4 accg[4], accu[4];
  #pragma unroll
  for (int i = 0; i < 4; ++i) { accg[i] = (floatx4){0,0,0,0}; accu[i] = (floatx4){0,0,0,0}; }

  float4 bv[4];

  auto loadB = [&](int kk) {
    #pragma unroll
    for (int j = 0; j < 4; ++j)
      bv[j] = *(const float4*)&gptr[(size_t)(kk + kb + j) * (2 * I_DIM)];
  };
  auto loadA = [&](int kk, int buf) {
    #pragma unroll
    for (int t = 0; t < 4; ++t)
      gld16(&arow[(size_t)agr[t] * H_DIM + kk + akc], &As[buf][(w * 32 + t * 8) * BK]);
  };
  auto writeB = [&]() {
    #pragma unroll
    for (int c = 0; c < 4; ++c) {
      const int r = rb0 + c;
      uint2 d;
      d.x = pk2(bv[0][c], bv[1][c]);
      d.y = pk2(bv[2][c], bv[3][c]);
      *(uint2*)&BsD[r * 32 + ((cwk ^ (r & 7)) << 2) + din] = d;
    }
  };
  auto compute = [&](int cb) {
    #pragma unroll
    for (int kf = 0; kf < 2; ++kf) {
      const int c = kf * 4 + q;
      const int ca = (c ^ cswz) * 8;          // swizzled chunk (A and B share the key)
      bf16x8 af[4], bg, bu;
      #pragma unroll
      for (int mi = 0; mi < 4; ++mi)
        af[mi] = *(const bf16x8*)&As[cb][(mrow + mi * 16 + lr) * BK + ca];
      bg = *(const bf16x8*)&Bs[(nhalf * 16 + lr) * BK + ca];
      bu = *(const bf16x8*)&Bs[(32 + nhalf * 16 + lr) * BK + ca];
      #pragma unroll
      for (int mi = 0; mi < 4; ++mi) {
        accg[mi] = __builtin_amdgcn_mfma_f32_16x16x32_bf16(af[mi], bg, accg[mi], 0, 0, 0);
        accu[mi] = __builtin_amdgcn_mfma_f32_16x16x32_bf16(af[mi], bu, accu[mi], 0, 0, 0);
      }
    }
  };

  // prologue: stage tile 0
  loadB(0);
  loadA(0, 0);
  writeB();
  __syncthreads();

  const int nk = H_DIM / BK;   // 16
  int cur = 0;
  for (int ki = 0; ki < nk - 1; ++ki) {
    const int kk = (ki + 1) * BK;
    loadB(kk);                  // 4 coalesced float4 loads
    loadA(kk, cur ^ 1);         // 4 gld16 -> other buffer
    __builtin_amdgcn_sched_barrier(0);
    compute(cur);
    bar_lgkm();                 // Bs readers done; prefetch still flying
    writeB();                   // counted vmcnt wait for bv only
    bar_full();
    cur ^= 1;
  }
  compute(cur);                 // tail

  #pragma unroll
  for (int mi = 0; mi < 4; ++mi)
    #pragma unroll
    for (int r = 0; r < 4; ++r) {
      int row_local = mrow + mi * 16 + q * 4 + r;
      if (row_local >= rows) continue;
      size_t orow = (size_t)(base + row0 + row_local) * I_DIM;
      float g = accg[mi][r], u = accu[mi][r];
      float s = g / (1.0f + __expf(-g)) * u;
      hb[orow + c0 + nhalf * 16 + lr] = f2bf(s);
    }
}

// ---------------- GEMM B: out = h @ Wd ----------------
__launch_bounds__(256, 4)
__global__ void k_gemm_b(const unsigned short* __restrict__ hb,
                         const float* __restrict__ wdn,
                         float* __restrict__ out,
                         const int* __restrict__ counts) {
  __shared__ unsigned short As[2][BM * BK];
  __shared__ unsigned short Bs[64 * BK];

  int e, row0, base, cnt;
  if (!tile_info(counts, blockIdx.y, e, row0, base, cnt)) return;
  const int rows = (cnt - row0 < BM) ? (cnt - row0) : BM;
  const int n0 = blockIdx.x * 64;

  const int tid = threadIdx.x;
  const int w = tid >> 6, l = tid & 63;
  const int lr = l & 15, q = l >> 4;
  const int asr = l >> 3;
  const int akc = ((l & 7) ^ asr) * 8;
  const int cswz = lr & 7;

  const int f4 = tid & 15;                    // 4-col chunk within 64
  const int kb = (tid >> 4) * 4;              // 0..60
  const int rb0 = f4 * 4;
  const float* gptr = wdn + (size_t)e * I_DIM * H_DIM + n0 + f4 * 4;
  unsigned int* BsD = (unsigned int*)Bs;
  const int cwk = kb >> 3;
  const int din = (kb >> 1) & 3;

  const int mhalf = w & 1, nhalf = w >> 1;
  const int mrow = mhalf * 64;
  const unsigned short* arow = hb + (size_t)(base + row0) * I_DIM;

  int agr[4];
  #pragma unroll
  for (int t = 0; t < 4; ++t) {
    int r = w * 32 + t * 8 + asr;
    agr[t] = (r < rows) ? r : rows - 1;
  }

  floatx4 acc[4][2];
  #pragma unroll
  for (int i = 0; i < 4; ++i)
    #pragma unroll
    for (int j = 0; j < 2; ++j) acc[i][j] = (floatx4){0,0,0,0};

  float4 bv[4];

  auto loadB = [&](int kk) {
    #pragma unroll
    for (int j = 0; j < 4; ++j)
      bv[j] = *(const float4*)&gptr[(size_t)(kk + kb + j) * H_DIM];
  };
  auto loadA = [&](int kk, int buf) {
    #pragma unroll
    for (int t = 0; t < 4; ++t)
      gld16(&arow[(size_t)agr[t] * I_DIM + kk + akc], &As[buf][(w * 32 + t * 8) * BK]);
  };
  auto writeB = [&]() {
    #pragma unroll
    for (int c = 0; c < 4; ++c) {
      const int r = rb0 + c;
      uint2 d;
      d.x = pk2(bv[0][c], bv[1][c]);
      d.y = pk2(bv[2][c], bv[3][c]);
      *(uint2*)&BsD[r * 32 + ((cwk ^ (r & 7)) << 2) + din] = d;
    }
  };
  auto compute = [&](int cb) {
    #pragma unroll
    for (int kf = 0; kf < 2; ++kf) {
      const int c = kf * 4 + q;
      const int ca = (c ^ cswz) * 8;
      bf16x8 af[4], bf[2];
      #pragma unroll
      for (int mi = 0; mi < 4; ++mi)
        af[mi] = *(const bf16x8*)&As[cb][(mrow + mi * 16 + lr) * BK + ca];
      #pragma unroll
      for (int ni = 0; ni < 2; ++ni)
        bf[ni] = *(const bf16x8*)&Bs[(nhalf * 32 + ni * 16 + lr) * BK + ca];
      #pragma unroll
      for (int mi = 0; mi < 4; ++mi)
        #pragma unroll
        for (int ni = 0; ni < 2; ++ni)
          acc[mi][ni] = __builtin_amdgcn_mfma_f32_16x16x32_bf16(af[mi], bf[ni], acc[mi][ni], 0, 0, 0);
    }
  };

  loadB(0);
  loadA(0, 0);
  writeB();
  __syncthreads();

  const int nk = I_DIM / BK;   // 8
  int cur = 0;
  for (int ki = 0; ki < nk - 1; ++ki) {
    const int kk = (ki + 1) * BK;
    loadB(kk);
    loadA(kk, cur ^ 1);
    __builtin_amdgcn_sched_barrier(0);
    compute(cur);
    bar_lgkm();
    writeB();
    bar_full();
    cur ^= 1;
  }
  compute(cur);

  #pragma unroll
  for (int mi = 0; mi < 4; ++mi)
    #pragma unroll
    for (int r = 0; r < 4; ++r) {
      int row_local = mrow + mi * 16 + q * 4 + r;
      if (row_local >= rows) continue;
      size_t orow = (size_t)(base + row0 + row_local) * H_DIM;
      #pragma unroll
      for (int ni = 0; ni < 2; ++ni)
        out[orow + n0 + nhalf * 32 + ni * 16 + lr] = acc[mi][ni][r];
    }
}

// ---------------- launch ----------------
extern "C" void kernel_launch(void* const* d_in, const int* in_sizes, int n_in,
                              void* d_out, int out_size, void* d_ws, size_t ws_size,
                              hipStream_t stream) {
  const float* x      = (const float*)d_in[0];
  const float* wgu    = (const float*)d_in[1];
  const float* wdn    = (const float*)d_in[2];
  const int*   counts = (const int*)d_in[3];
  float* out = (float*)d_out;

  unsigned char* ws = (unsigned char*)d_ws;
  unsigned short* xb = (unsigned short*)(ws);            // 8 MB
  unsigned short* hb = (unsigned short*)(ws + 8388608);  // 4 MB

  k_cvt<<<2048, 256, 0, stream>>>(x, xb);
  k_gemm_a<<<dim3(I_DIM / 32, 48), 256, 0, stream>>>(xb, wgu, hb, counts);   // 768 blocks, 4/CU
  k_gemm_b<<<dim3(H_DIM / 64, 48), 256, 0, stream>>>(hb, wdn, out, counts);  // 768 blocks, 4/CU
}